// Round 3
// baseline (623.715 us; speedup 1.0000x reference)
//
#include <hip/hip_runtime.h>
#include <cstdint>
#include <cstddef>

// Problem constants
#define B_   4
#define S_   2048
#define HID_ 768
#define H_   12
#define D_   64
#define BH_  (B_*H_)        // 48
#define M1_  (B_*S_)        // 8192
#define N1_  (3*HID_)       // 2304
#define PWR  65.5f          // D + alpha

typedef _Float16 f16;
using half8    = __attribute__((ext_vector_type(8))) _Float16;
using float4_t = __attribute__((ext_vector_type(4))) float;

// HW transcendentals: v_exp_f32 (2^x) and v_log_f32 (log2 x)
__device__ __forceinline__ float fexp2(float x) { return __builtin_amdgcn_exp2f(x); }
__device__ __forceinline__ float flog2(float x) { return __builtin_amdgcn_logf(x); }

// ---------------------------------------------------------------------------
// Convert x fp32 -> fp16 (vectorized 4/thread)
__global__ __launch_bounds__(256) void k_convert_x(const float* __restrict__ x,
                                                   f16* __restrict__ xh) {
  int i = blockIdx.x * 256 + threadIdx.x;
  const float4* xv = (const float4*)x;
  float4 v = xv[i];
  f16 tmp[4] = {(f16)v.x, (f16)v.y, (f16)v.z, (f16)v.w};
  *(uint2*)(xh + 4 * (size_t)i) = *(uint2*)tmp;
}

// Transpose + convert weight: w[K][N] fp32 -> wt[N][K] fp16
__global__ __launch_bounds__(256) void k_transpose_w(const float* __restrict__ w,
                                                     f16* __restrict__ wt,
                                                     int N, int K) {
  int n = blockIdx.x * 256 + threadIdx.x;
  int k = blockIdx.y;
  if (n < N) wt[(size_t)n * K + k] = (f16)w[(size_t)k * N + n];
}

// ---------------------------------------------------------------------------
// QKV GEMM: A = xh [8192][768] fp16, Bt = wqkv_t [2304][768] fp16.
// Epilogue scatters into Qh/Kh [bh][s][d] and Vt [bh][d][s] (fp16) + bias.
__global__ __launch_bounds__(256) void k_gemm_qkv(
    const f16* __restrict__ A, const f16* __restrict__ Bt,
    const float* __restrict__ bias,
    f16* __restrict__ Qh, f16* __restrict__ Kh, f16* __restrict__ Vt) {
  __shared__ f16 As[128][72];
  __shared__ f16 Bs[128][72];
  int tid  = threadIdx.x;
  int wave = tid >> 6, lane = tid & 63;
  int quad = lane >> 4, l15 = lane & 15;
  int wm = wave >> 1, wn = wave & 1;
  int m0 = blockIdx.y * 128;
  int n0 = blockIdx.x * 128;

  float4_t acc[4][4] = {};

  // staging: r in [0,32), c8 covers 64 cols with 8 f16 (one uint4) per thread
  int r  = tid >> 3;
  int c8 = (tid & 7) * 8;

  for (int k0 = 0; k0 < 768; k0 += 64) {
    for (int rr = 0; rr < 128; rr += 32) {
      *(uint4*)(&As[r + rr][c8]) =
          *(const uint4*)(A  + (size_t)(m0 + r + rr) * 768 + k0 + c8);
      *(uint4*)(&Bs[r + rr][c8]) =
          *(const uint4*)(Bt + (size_t)(n0 + r + rr) * 768 + k0 + c8);
    }
    __syncthreads();
    half8 af[4][2], bf[4][2];
    for (int mt = 0; mt < 4; mt++)
      for (int ks = 0; ks < 2; ks++)
        af[mt][ks] = *(const half8*)(&As[wm * 64 + mt * 16 + l15][ks * 32 + quad * 8]);
    for (int nt = 0; nt < 4; nt++)
      for (int ks = 0; ks < 2; ks++)
        bf[nt][ks] = *(const half8*)(&Bs[wn * 64 + nt * 16 + l15][ks * 32 + quad * 8]);
    for (int ks = 0; ks < 2; ks++)
      for (int mt = 0; mt < 4; mt++)
        for (int nt = 0; nt < 4; nt++)
          acc[mt][nt] = __builtin_amdgcn_mfma_f32_16x16x32_f16(af[mt][ks], bf[nt][ks],
                                                               acc[mt][nt], 0, 0, 0);
    __syncthreads();
  }

  for (int mt = 0; mt < 4; mt++)
    for (int nt = 0; nt < 4; nt++)
      for (int rg = 0; rg < 4; rg++) {
        int R = m0 + wm * 64 + mt * 16 + quad * 4 + rg;
        int n = n0 + wn * 64 + nt * 16 + l15;
        float v = acc[mt][nt][rg] + bias[n];
        int b = R >> 11, s = R & 2047;
        int which = n / 768;
        int rem = n - which * 768;
        int h = rem >> 6, d = rem & 63;
        int bh = b * 12 + h;
        f16 hv = (f16)v;
        if (which == 0)      Qh[((size_t)bh * 2048 + s) * 64 + d] = hv;
        else if (which == 1) Kh[((size_t)bh * 2048 + s) * 64 + d] = hv;
        else                 Vt[((size_t)bh * 64 + d) * 2048 + s] = hv;
      }
}

// ---------------------------------------------------------------------------
// Squared norms of fp16-rounded q,k rows (fp32): consistency with MFMA dot.
__global__ __launch_bounds__(256) void k_norms(const f16* __restrict__ Qh,
                                               const f16* __restrict__ Kh,
                                               float* __restrict__ qq,
                                               float* __restrict__ kk) {
  int i = blockIdx.x * 256 + threadIdx.x;
  if (i >= BH_ * S_) return;
  const f16* p = Qh + (size_t)i * 64;
  float s1 = 0.f, s2 = 0.f;
  for (int d = 0; d < 64; d += 8) {
    half8 v = *(const half8*)(p + d);
    for (int j = 0; j < 8; j++) { float t = (float)v[j]; s1 += t * t; }
  }
  p = Kh + (size_t)i * 64;
  for (int d = 0; d < 64; d += 8) {
    half8 v = *(const half8*)(p + d);
    for (int j = 0; j < 8; j++) { float t = (float)v[j]; s2 += t * t; }
  }
  qq[i] = s1;
  kk[i] = s2;
}

// ---------------------------------------------------------------------------
// Pass 1: column logsumexp of c_ij = -65.5*log2(1+g_ij) over i, per (bh, j).
// Block = (bh, 64 j's); 4 waves each own 16 j rows; loop over 32 i-tiles.
__global__ __launch_bounds__(256) void k_colsum(
    const f16* __restrict__ Qh, const f16* __restrict__ Kh,
    const float* __restrict__ qq, const float* __restrict__ kk,
    float* __restrict__ lognc) {
  int bh = blockIdx.y;
  int j0 = blockIdx.x * 64;
  __shared__ f16 Kt[64][72];
  __shared__ f16 Qt[64][72];
  __shared__ float kks[64];
  __shared__ float qqs[64];
  int tid = threadIdx.x;
  int wave = tid >> 6, lane = tid & 63, quad = lane >> 4, l15 = lane & 15;
  int r = tid >> 3, c8 = (tid & 7) * 8;
  const f16* Kb = Kh + (size_t)bh * 2048 * 64;
  const f16* Qb = Qh + (size_t)bh * 2048 * 64;

  for (int rr = 0; rr < 64; rr += 32)
    *(uint4*)(&Kt[r + rr][c8]) = *(const uint4*)(Kb + (size_t)(j0 + r + rr) * 64 + c8);
  if (tid < 64) kks[tid] = kk[bh * 2048 + j0 + tid];
  __syncthreads();

  half8 af[2];
  for (int ks = 0; ks < 2; ks++)
    af[ks] = *(const half8*)(&Kt[wave * 16 + l15][ks * 32 + quad * 8]);
  float kkv[4];
  for (int t = 0; t < 4; t++) kkv[t] = kks[wave * 16 + quad * 4 + t];

  float rm[4], rs[4];
  for (int t = 0; t < 4; t++) { rm[t] = -1e30f; rs[t] = 0.f; }

  for (int it = 0; it < 32; it++) {
    __syncthreads();
    int i0 = it * 64;
    for (int rr = 0; rr < 64; rr += 32)
      *(uint4*)(&Qt[r + rr][c8]) = *(const uint4*)(Qb + (size_t)(i0 + r + rr) * 64 + c8);
    if (tid < 64) qqs[tid] = qq[bh * 2048 + i0 + tid];
    __syncthreads();

    float4_t acc[4] = {};
    for (int nt = 0; nt < 4; nt++)
      for (int ks = 0; ks < 2; ks++) {
        half8 bfv = *(const half8*)(&Qt[nt * 16 + l15][ks * 32 + quad * 8]);
        acc[nt] = __builtin_amdgcn_mfma_f32_16x16x32_f16(af[ks], bfv, acc[nt], 0, 0, 0);
      }

    for (int rg = 0; rg < 4; rg++) {
      float c[4];
      for (int nt = 0; nt < 4; nt++) {
        float dot = acc[nt][rg];
        float d2 = kkv[rg] + qqs[nt * 16 + l15] - 2.f * dot;
        d2 = fmaxf(d2, 0.f);
        float g = sqrtf(d2);
        c[nt] = -PWR * flog2(1.f + g);
      }
      float tm = fmaxf(fmaxf(c[0], c[1]), fmaxf(c[2], c[3]));
      for (int m = 1; m < 16; m <<= 1) tm = fmaxf(tm, __shfl_xor(tm, m, 16));
      float nm = fmaxf(rm[rg], tm);
      float ts = fexp2(c[0] - nm) + fexp2(c[1] - nm) +
                 fexp2(c[2] - nm) + fexp2(c[3] - nm);
      for (int m = 1; m < 16; m <<= 1) ts += __shfl_xor(ts, m, 16);
      rs[rg] = rs[rg] * fexp2(rm[rg] - nm) + ts;
      rm[rg] = nm;
    }
  }
  if (l15 == 0)
    for (int rg = 0; rg < 4; rg++) {
      int j = j0 + wave * 16 + quad * 4 + rg;
      lognc[bh * 2048 + j] = rm[rg] + flog2(rs[rg]);
    }
}

// ---------------------------------------------------------------------------
// Pass 2: flash-style. Logits M = c - 0.5*logNC[j]; online softmax; O += P@V.
__global__ __launch_bounds__(256) void k_flash(
    const f16* __restrict__ Qh, const f16* __restrict__ Kh, const f16* __restrict__ Vt,
    const float* __restrict__ qq, const float* __restrict__ kk,
    const float* __restrict__ lognc, f16* __restrict__ attn) {
  int bh = blockIdx.y;
  int i0 = blockIdx.x * 64;
  __shared__ f16 Qt[64][72];
  __shared__ f16 Kt[64][72];
  __shared__ f16 Vts[64][72];       // [d][j]
  __shared__ float qqs[64], kks[64], lns[64];
  __shared__ f16 Plds[4][16][72];   // per-wave P tile, stride 72 keeps 16B align
  int tid = threadIdx.x;
  int wave = tid >> 6, lane = tid & 63, quad = lane >> 4, l15 = lane & 15;
  int r = tid >> 3, c8 = (tid & 7) * 8;
  const f16* Qb = Qh + (size_t)bh * 2048 * 64;
  const f16* Kb = Kh + (size_t)bh * 2048 * 64;
  const f16* Vb = Vt + (size_t)bh * 64 * 2048;

  for (int rr = 0; rr < 64; rr += 32)
    *(uint4*)(&Qt[r + rr][c8]) = *(const uint4*)(Qb + (size_t)(i0 + r + rr) * 64 + c8);
  if (tid < 64) qqs[tid] = qq[bh * 2048 + i0 + tid];
  __syncthreads();

  half8 af[2];
  for (int ks = 0; ks < 2; ks++)
    af[ks] = *(const half8*)(&Qt[wave * 16 + l15][ks * 32 + quad * 8]);
  float qv[4];
  for (int t = 0; t < 4; t++) qv[t] = qqs[wave * 16 + quad * 4 + t];

  float om[4], os[4];
  float4_t Oacc[4] = {};
  for (int t = 0; t < 4; t++) { om[t] = -1e30f; os[t] = 0.f; }

  for (int jt = 0; jt < 32; jt++) {
    __syncthreads();   // prev iter's Kt/Vts reads done
    int j0 = jt * 64;
    for (int rr = 0; rr < 64; rr += 32) {
      *(uint4*)(&Kt[r + rr][c8]) =
          *(const uint4*)(Kb + (size_t)(j0 + r + rr) * 64 + c8);
      *(uint4*)(&Vts[r + rr][c8]) =
          *(const uint4*)(Vb + (size_t)(r + rr) * 2048 + j0 + c8);
    }
    if (tid < 64) {
      kks[tid] = kk[bh * 2048 + j0 + tid];
      lns[tid] = lognc[bh * 2048 + j0 + tid];
    }
    __syncthreads();

    float4_t acc[4] = {};
    for (int nt = 0; nt < 4; nt++)
      for (int ks = 0; ks < 2; ks++) {
        half8 bfv = *(const half8*)(&Kt[nt * 16 + l15][ks * 32 + quad * 8]);
        acc[nt] = __builtin_amdgcn_mfma_f32_16x16x32_f16(af[ks], bfv, acc[nt], 0, 0, 0);
      }

    float pvv[4][4];
    for (int rg = 0; rg < 4; rg++) {
      float c[4];
      for (int nt = 0; nt < 4; nt++) {
        float dot = acc[nt][rg];
        float d2 = qv[rg] + kks[nt * 16 + l15] - 2.f * dot;
        d2 = fmaxf(d2, 0.f);
        float g = sqrtf(d2);
        c[nt] = -PWR * flog2(1.f + g) - 0.5f * lns[nt * 16 + l15];
      }
      float tm = fmaxf(fmaxf(c[0], c[1]), fmaxf(c[2], c[3]));
      for (int m = 1; m < 16; m <<= 1) tm = fmaxf(tm, __shfl_xor(tm, m, 16));
      float nm = fmaxf(om[rg], tm);
      float alpha = fexp2(om[rg] - nm);
      om[rg] = nm;
      float ts = 0.f;
      for (int nt = 0; nt < 4; nt++) {
        pvv[nt][rg] = fexp2(c[nt] - nm);
        ts += pvv[nt][rg];
      }
      for (int m = 1; m < 16; m <<= 1) ts += __shfl_xor(ts, m, 16);
      os[rg] = os[rg] * alpha + ts;
      for (int nt = 0; nt < 4; nt++) Oacc[nt][rg] *= alpha;
    }

    for (int nt = 0; nt < 4; nt++)
      for (int rg = 0; rg < 4; rg++)
        Plds[wave][quad * 4 + rg][nt * 16 + l15] = (f16)pvv[nt][rg];
    __syncthreads();   // order P writes (cross-lane) before A-frag reads

    half8 pa[2];
    for (int ks = 0; ks < 2; ks++)
      pa[ks] = *(const half8*)(&Plds[wave][l15][ks * 32 + quad * 8]);
    for (int nt = 0; nt < 4; nt++)
      for (int ks = 0; ks < 2; ks++) {
        half8 vbv = *(const half8*)(&Vts[nt * 16 + l15][ks * 32 + quad * 8]);
        Oacc[nt] = __builtin_amdgcn_mfma_f32_16x16x32_f16(pa[ks], vbv, Oacc[nt], 0, 0, 0);
      }
  }

  int b = bh / 12, h = bh - b * 12;
  for (int nt = 0; nt < 4; nt++)
    for (int rg = 0; rg < 4; rg++) {
      int s = i0 + wave * 16 + quad * 4 + rg;
      int d = nt * 16 + l15;
      float v = Oacc[nt][rg] / os[rg];
      attn[((size_t)(b * 2048 + s)) * 768 + h * 64 + d] = (f16)v;
    }
}

// ---------------------------------------------------------------------------
// Output GEMM: attn [8192][768] fp16 @ wout_t [768][768] fp16 + b_out -> fp32
__global__ __launch_bounds__(256) void k_gemm_out(
    const f16* __restrict__ A, const f16* __restrict__ Bt,
    const float* __restrict__ bias, float* __restrict__ out) {
  __shared__ f16 As[128][72];
  __shared__ f16 Bs[128][72];
  int tid  = threadIdx.x;
  int wave = tid >> 6, lane = tid & 63;
  int quad = lane >> 4, l15 = lane & 15;
  int wm = wave >> 1, wn = wave & 1;
  int m0 = blockIdx.y * 128;
  int n0 = blockIdx.x * 128;

  float4_t acc[4][4] = {};
  int r  = tid >> 3;
  int c8 = (tid & 7) * 8;

  for (int k0 = 0; k0 < 768; k0 += 64) {
    for (int rr = 0; rr < 128; rr += 32) {
      *(uint4*)(&As[r + rr][c8]) =
          *(const uint4*)(A  + (size_t)(m0 + r + rr) * 768 + k0 + c8);
      *(uint4*)(&Bs[r + rr][c8]) =
          *(const uint4*)(Bt + (size_t)(n0 + r + rr) * 768 + k0 + c8);
    }
    __syncthreads();
    half8 af[4][2], bf[4][2];
    for (int mt = 0; mt < 4; mt++)
      for (int ks = 0; ks < 2; ks++)
        af[mt][ks] = *(const half8*)(&As[wm * 64 + mt * 16 + l15][ks * 32 + quad * 8]);
    for (int nt = 0; nt < 4; nt++)
      for (int ks = 0; ks < 2; ks++)
        bf[nt][ks] = *(const half8*)(&Bs[wn * 64 + nt * 16 + l15][ks * 32 + quad * 8]);
    for (int ks = 0; ks < 2; ks++)
      for (int mt = 0; mt < 4; mt++)
        for (int nt = 0; nt < 4; nt++)
          acc[mt][nt] = __builtin_amdgcn_mfma_f32_16x16x32_f16(af[mt][ks], bf[nt][ks],
                                                               acc[mt][nt], 0, 0, 0);
    __syncthreads();
  }

  for (int mt = 0; mt < 4; mt++)
    for (int nt = 0; nt < 4; nt++)
      for (int rg = 0; rg < 4; rg++) {
        int R = m0 + wm * 64 + mt * 16 + quad * 4 + rg;
        int n = n0 + wn * 64 + nt * 16 + l15;
        out[(size_t)R * 768 + n] = acc[mt][nt][rg] + bias[n];
      }
}

// ---------------------------------------------------------------------------
extern "C" void kernel_launch(void* const* d_in, const int* in_sizes, int n_in,
                              void* d_out, int out_size, void* d_ws, size_t ws_size,
                              hipStream_t stream) {
  const float* x     = (const float*)d_in[0];
  const float* Wqkv  = (const float*)d_in[1];
  const float* bqkv  = (const float*)d_in[2];
  const float* Wout  = (const float*)d_in[3];
  const float* bout  = (const float*)d_in[4];
  float* out = (float*)d_out;

  char* ws = (char*)d_ws;
  size_t off = 0;
  f16* xh     = (f16*)(ws + off);           // also reused for attn
  off += (size_t)M1_ * HID_ * 2;            // 12,582,912
  f16* wqkvt  = (f16*)(ws + off); off += (size_t)N1_ * HID_ * 2;   // 3,538,944
  f16* woutt  = (f16*)(ws + off); off += (size_t)HID_ * HID_ * 2;  // 1,179,648
  f16* Qh     = (f16*)(ws + off); off += (size_t)BH_ * S_ * D_ * 2;
  f16* Kh     = (f16*)(ws + off); off += (size_t)BH_ * S_ * D_ * 2;
  f16* Vt     = (f16*)(ws + off); off += (size_t)BH_ * S_ * D_ * 2;
  float* qq   = (float*)(ws + off); off += (size_t)BH_ * S_ * 4;
  float* kk   = (float*)(ws + off); off += (size_t)BH_ * S_ * 4;
  float* lognc= (float*)(ws + off); off += (size_t)BH_ * S_ * 4;
  f16* attn   = xh;  // xh is dead after k_gemm_qkv; alias to save workspace

  // 1. converts / transposes
  k_convert_x<<<dim3(M1_ * HID_ / 4 / 256), dim3(256), 0, stream>>>(x, xh);
  k_transpose_w<<<dim3(9, 768), dim3(256), 0, stream>>>(Wqkv, wqkvt, N1_, HID_);
  k_transpose_w<<<dim3(3, 768), dim3(256), 0, stream>>>(Wout, woutt, HID_, HID_);

  // 2. QKV projection
  k_gemm_qkv<<<dim3(N1_ / 128, M1_ / 128), dim3(256), 0, stream>>>(
      xh, wqkvt, bqkv, Qh, Kh, Vt);

  // 3. norms
  k_norms<<<dim3(BH_ * S_ / 256), dim3(256), 0, stream>>>(Qh, Kh, qq, kk);

  // 4. column logsumexp
  k_colsum<<<dim3(S_ / 64, BH_), dim3(256), 0, stream>>>(Qh, Kh, qq, kk, lognc);

  // 5. flash attention with two-sided normalized kernel
  k_flash<<<dim3(S_ / 64, BH_), dim3(256), 0, stream>>>(
      Qh, Kh, Vt, qq, kk, lognc, attn);

  // 6. output projection
  k_gemm_out<<<dim3(HID_ / 128, M1_ / 128), dim3(256), 0, stream>>>(
      attn, woutt, bout, out);
}

// Round 6
// 613.765 us; speedup vs baseline: 1.0162x; 1.0162x over previous
//
#include <hip/hip_runtime.h>
#include <cstdint>
#include <cstddef>

// Problem constants
#define B_   4
#define S_   2048
#define HID_ 768
#define H_   12
#define D_   64
#define BH_  (B_*H_)        // 48
#define M1_  (B_*S_)        // 8192
#define N1_  (3*HID_)       // 2304
#define PWR  65.5f          // D + alpha

typedef _Float16 f16;
using half4    = __attribute__((ext_vector_type(4))) _Float16;
using half8    = __attribute__((ext_vector_type(8))) _Float16;
using float4_t = __attribute__((ext_vector_type(4))) float;

__device__ __forceinline__ float fexp2(float x) { return __builtin_amdgcn_exp2f(x); }
__device__ __forceinline__ float flog2(float x) { return __builtin_amdgcn_logf(x); }

// ---------------------------------------------------------------------------
__global__ __launch_bounds__(256) void k_convert_x(const float* __restrict__ x,
                                                   f16* __restrict__ xh) {
  int i = blockIdx.x * 256 + threadIdx.x;
  const float4* xv = (const float4*)x;
  float4 v = xv[i];
  f16 tmp[4] = {(f16)v.x, (f16)v.y, (f16)v.z, (f16)v.w};
  *(uint2*)(xh + 4 * (size_t)i) = *(uint2*)tmp;
}

__global__ __launch_bounds__(256) void k_transpose_w(const float* __restrict__ w,
                                                     f16* __restrict__ wt,
                                                     int N, int K) {
  int n = blockIdx.x * 256 + threadIdx.x;
  int k = blockIdx.y;
  if (n < N) wt[(size_t)n * K + k] = (f16)w[(size_t)k * N + n];
}

// ---------------------------------------------------------------------------
__global__ __launch_bounds__(256) void k_gemm_qkv(
    const f16* __restrict__ A, const f16* __restrict__ Bt,
    const float* __restrict__ bias,
    f16* __restrict__ Qh, f16* __restrict__ Kh, f16* __restrict__ Vt) {
  __shared__ f16 As[128][72];
  __shared__ f16 Bs[128][72];
  int tid  = threadIdx.x;
  int wave = tid >> 6, lane = tid & 63;
  int quad = lane >> 4, l15 = lane & 15;
  int wm = wave >> 1, wn = wave & 1;
  int m0 = blockIdx.y * 128;
  int n0 = blockIdx.x * 128;

  float4_t acc[4][4] = {};
  int r  = tid >> 3;
  int c8 = (tid & 7) * 8;

  for (int k0 = 0; k0 < 768; k0 += 64) {
    for (int rr = 0; rr < 128; rr += 32) {
      *(uint4*)(&As[r + rr][c8]) =
          *(const uint4*)(A  + (size_t)(m0 + r + rr) * 768 + k0 + c8);
      *(uint4*)(&Bs[r + rr][c8]) =
          *(const uint4*)(Bt + (size_t)(n0 + r + rr) * 768 + k0 + c8);
    }
    __syncthreads();
    half8 af[4][2], bf[4][2];
    for (int mt = 0; mt < 4; mt++)
      for (int ks = 0; ks < 2; ks++)
        af[mt][ks] = *(const half8*)(&As[wm * 64 + mt * 16 + l15][ks * 32 + quad * 8]);
    for (int nt = 0; nt < 4; nt++)
      for (int ks = 0; ks < 2; ks++)
        bf[nt][ks] = *(const half8*)(&Bs[wn * 64 + nt * 16 + l15][ks * 32 + quad * 8]);
    for (int ks = 0; ks < 2; ks++)
      for (int mt = 0; mt < 4; mt++)
        for (int nt = 0; nt < 4; nt++)
          acc[mt][nt] = __builtin_amdgcn_mfma_f32_16x16x32_f16(af[mt][ks], bf[nt][ks],
                                                               acc[mt][nt], 0, 0, 0);
    __syncthreads();
  }

  for (int mt = 0; mt < 4; mt++)
    for (int nt = 0; nt < 4; nt++)
      for (int rg = 0; rg < 4; rg++) {
        int R = m0 + wm * 64 + mt * 16 + quad * 4 + rg;
        int n = n0 + wn * 64 + nt * 16 + l15;
        float v = acc[mt][nt][rg] + bias[n];
        int b = R >> 11, s = R & 2047;
        int which = n / 768;
        int rem = n - which * 768;
        int h = rem >> 6, d = rem & 63;
        int bh = b * 12 + h;
        f16 hv = (f16)v;
        if (which == 0)      Qh[((size_t)bh * 2048 + s) * 64 + d] = hv;
        else if (which == 1) Kh[((size_t)bh * 2048 + s) * 64 + d] = hv;
        else                 Vt[((size_t)bh * 64 + d) * 2048 + s] = hv;
      }
}

// ---------------------------------------------------------------------------
__global__ __launch_bounds__(256) void k_norms(const f16* __restrict__ Qh,
                                               const f16* __restrict__ Kh,
                                               float* __restrict__ qq,
                                               float* __restrict__ kk) {
  int i = blockIdx.x * 256 + threadIdx.x;
  if (i >= BH_ * S_) return;
  const f16* p = Qh + (size_t)i * 64;
  float s1 = 0.f, s2 = 0.f;
  for (int d = 0; d < 64; d += 8) {
    half8 v = *(const half8*)(p + d);
    for (int j = 0; j < 8; j++) { float t = (float)v[j]; s1 += t * t; }
  }
  p = Kh + (size_t)i * 64;
  for (int d = 0; d < 64; d += 8) {
    half8 v = *(const half8*)(p + d);
    for (int j = 0; j < 8; j++) { float t = (float)v[j]; s2 += t * t; }
  }
  qq[i] = s1;
  kk[i] = s2;
}

// ---------------------------------------------------------------------------
// Pass 1: column logsumexp of c_ij over i. Online max tracked as running
// min-d2 per column (c monotone in d2): common path has NO cross-lane ops.
__global__ __launch_bounds__(256) void k_colsum(
    const f16* __restrict__ Qh, const f16* __restrict__ Kh,
    const float* __restrict__ qq, const float* __restrict__ kk,
    float* __restrict__ lognc) {
  int bh = blockIdx.y;
  int j0 = blockIdx.x * 64;
  __shared__ f16 Kt[64][72];
  __shared__ f16 Qt[64][72];
  __shared__ float kks[64];
  __shared__ float qqs[64];
  int tid = threadIdx.x;
  int wave = tid >> 6, lane = tid & 63, quad = lane >> 4, l15 = lane & 15;
  int r = tid >> 3, c8 = (tid & 7) * 8;
  const f16* Kb = Kh + (size_t)bh * 2048 * 64;
  const f16* Qb = Qh + (size_t)bh * 2048 * 64;

  for (int rr = 0; rr < 64; rr += 32)
    *(uint4*)(&Kt[r + rr][c8]) = *(const uint4*)(Kb + (size_t)(j0 + r + rr) * 64 + c8);
  if (tid < 64) kks[tid] = kk[bh * 2048 + j0 + tid];
  __syncthreads();

  half8 af[2];
  for (int ks = 0; ks < 2; ks++)
    af[ks] = *(const half8*)(&Kt[wave * 16 + l15][ks * 32 + quad * 8]);
  float kkv[4];
  for (int t = 0; t < 4; t++) kkv[t] = kks[wave * 16 + quad * 4 + t];

  float rm[4], rmind2[4], rs[4];
  for (int t = 0; t < 4; t++) { rm[t] = -1e30f; rmind2[t] = 1e30f; rs[t] = 0.f; }

  for (int it = 0; it < 32; it++) {
    __syncthreads();
    int i0 = it * 64;
    for (int rr = 0; rr < 64; rr += 32)
      *(uint4*)(&Qt[r + rr][c8]) = *(const uint4*)(Qb + (size_t)(i0 + r + rr) * 64 + c8);
    if (tid < 64) qqs[tid] = qq[bh * 2048 + i0 + tid];
    __syncthreads();

    float4_t acc[4] = {};
    for (int nt = 0; nt < 4; nt++)
      for (int ks = 0; ks < 2; ks++) {
        half8 bfv = *(const half8*)(&Qt[nt * 16 + l15][ks * 32 + quad * 8]);
        acc[nt] = __builtin_amdgcn_mfma_f32_16x16x32_f16(af[ks], bfv, acc[nt], 0, 0, 0);
      }

    float d2v[4][4];
    float lmn[4] = {1e30f, 1e30f, 1e30f, 1e30f};
    for (int nt = 0; nt < 4; nt++) {
      float qn = qqs[nt * 16 + l15];
      for (int rg = 0; rg < 4; rg++) {
        float d2 = fmaxf(fmaf(-2.f, acc[nt][rg], kkv[rg] + qn), 0.f);
        d2v[nt][rg] = d2;
        lmn[rg] = fminf(lmn[rg], d2);
      }
    }
    bool noimp = (lmn[0] >= rmind2[0]) & (lmn[1] >= rmind2[1]) &
                 (lmn[2] >= rmind2[2]) & (lmn[3] >= rmind2[3]);
    if (!__all(noimp)) {   // rare: some column's max improved
      for (int rg = 0; rg < 4; rg++) {
        float t = lmn[rg];
        for (int m = 1; m < 16; m <<= 1) t = fminf(t, __shfl_xor(t, m, 16));
        t = fminf(t, rmind2[rg]);
        float nm = -PWR * flog2(1.f + sqrtf(t));
        rs[rg] *= fexp2(rm[rg] - nm);
        rm[rg] = nm; rmind2[rg] = t;
      }
    }
    for (int nt = 0; nt < 4; nt++)
      for (int rg = 0; rg < 4; rg++) {
        float g = sqrtf(d2v[nt][rg]);
        rs[rg] += fexp2(fmaf(-PWR, flog2(1.f + g), -rm[rg]));
      }
  }
  for (int rg = 0; rg < 4; rg++) {
    float s = rs[rg];
    for (int m = 1; m < 16; m <<= 1) s += __shfl_xor(s, m, 16);
    if (l15 == 0) {
      int j = j0 + wave * 16 + quad * 4 + rg;
      lognc[bh * 2048 + j] = rm[rg] + flog2(s);
    }
  }
}

// ---------------------------------------------------------------------------
// Pass 2: flash with biased logits m = c - 0.5*lognc_j (exact R3 semantics).
// Lazy online max: cross-lane reduce + rescale only when a tile actually
// raises some row's max (checked with per-lane compares + one __all).
__global__ __launch_bounds__(256) void k_flash(
    const f16* __restrict__ Qh, const f16* __restrict__ Kh, const f16* __restrict__ Vt,
    const float* __restrict__ qq, const float* __restrict__ kk,
    const float* __restrict__ lognc, f16* __restrict__ attn) {
  int bh = blockIdx.y;
  int i0 = blockIdx.x * 64;
  __shared__ f16 Qt[64][72];
  __shared__ f16 Kt[64][72];
  __shared__ f16 Vts[64][72];           // [d][j]
  __shared__ float qqs[64], kks[64], lns[64];   // lns = -0.5*log2(N_C)
  __shared__ f16 Plds[4][16][68];       // stride 68: quads hit disjoint banks
  int tid = threadIdx.x;
  int wave = tid >> 6, lane = tid & 63, quad = lane >> 4, l15 = lane & 15;
  int r = tid >> 3, c8 = (tid & 7) * 8;
  const f16* Qb = Qh + (size_t)bh * 2048 * 64;
  const f16* Kb = Kh + (size_t)bh * 2048 * 64;
  const f16* Vb = Vt + (size_t)bh * 64 * 2048;

  for (int rr = 0; rr < 64; rr += 32)
    *(uint4*)(&Qt[r + rr][c8]) = *(const uint4*)(Qb + (size_t)(i0 + r + rr) * 64 + c8);
  if (tid < 64) qqs[tid] = qq[bh * 2048 + i0 + tid];
  __syncthreads();

  half8 af[2];
  for (int ks = 0; ks < 2; ks++)
    af[ks] = *(const half8*)(&Qt[wave * 16 + l15][ks * 32 + quad * 8]);
  float qv[4];
  for (int t = 0; t < 4; t++) qv[t] = qqs[wave * 16 + quad * 4 + t];

  float rm[4], os[4];
  float4_t Oacc[4] = {};
  for (int t = 0; t < 4; t++) { rm[t] = -1e30f; os[t] = 0.f; }

  for (int jt = 0; jt < 32; jt++) {
    __syncthreads();
    int j0 = jt * 64;
    for (int rr = 0; rr < 64; rr += 32) {
      *(uint4*)(&Kt[r + rr][c8]) =
          *(const uint4*)(Kb + (size_t)(j0 + r + rr) * 64 + c8);
      *(uint4*)(&Vts[r + rr][c8]) =
          *(const uint4*)(Vb + (size_t)(r + rr) * 2048 + j0 + c8);
    }
    if (tid < 64) {
      kks[tid] = kk[bh * 2048 + j0 + tid];
      lns[tid] = -0.5f * lognc[bh * 2048 + j0 + tid];
    }
    __syncthreads();

    float4_t acc[4] = {};
    for (int nt = 0; nt < 4; nt++)
      for (int ks = 0; ks < 2; ks++) {
        half8 bfv = *(const half8*)(&Kt[nt * 16 + l15][ks * 32 + quad * 8]);
        acc[nt] = __builtin_amdgcn_mfma_f32_16x16x32_f16(af[ks], bfv, acc[nt], 0, 0, 0);
      }

    // biased logits + per-lane tile max per row
    float mv[4][4];
    float lmx[4] = {-1e30f, -1e30f, -1e30f, -1e30f};
    for (int nt = 0; nt < 4; nt++) {
      float kn = kks[nt * 16 + l15];
      float bias = lns[nt * 16 + l15];
      for (int rg = 0; rg < 4; rg++) {
        float d2 = fmaxf(fmaf(-2.f, acc[nt][rg], qv[rg] + kn), 0.f);
        float g = sqrtf(d2);
        float m = fmaf(-PWR, flog2(1.f + g), bias);
        mv[nt][rg] = m;
        lmx[rg] = fmaxf(lmx[rg], m);
      }
    }
    bool noimp = (lmx[0] <= rm[0]) & (lmx[1] <= rm[1]) &
                 (lmx[2] <= rm[2]) & (lmx[3] <= rm[3]);
    if (!__all(noimp)) {   // rare: some row's max improved -> reduce + rescale
      for (int rg = 0; rg < 4; rg++) {
        float t = lmx[rg];
        for (int m = 1; m < 16; m <<= 1) t = fmaxf(t, __shfl_xor(t, m, 16));
        t = fmaxf(t, rm[rg]);
        float a = fexp2(rm[rg] - t);
        os[rg] *= a;
        Oacc[0][rg] *= a; Oacc[1][rg] *= a; Oacc[2][rg] *= a; Oacc[3][rg] *= a;
        rm[rg] = t;
      }
    }

    for (int nt = 0; nt < 4; nt++)
      for (int rg = 0; rg < 4; rg++) {
        float p = fexp2(mv[nt][rg] - rm[rg]);   // <= 1 guaranteed
        os[rg] += p;
        Plds[wave][quad * 4 + rg][nt * 16 + l15] = (f16)p;
      }
    __syncthreads();   // order P writes before A-frag reads

    half8 pa[2];
    for (int ks = 0; ks < 2; ks++) {
      half4 plo = *(const half4*)(&Plds[wave][l15][ks * 32 + quad * 8]);
      half4 phi = *(const half4*)(&Plds[wave][l15][ks * 32 + quad * 8 + 4]);
      for (int t = 0; t < 4; t++) { pa[ks][t] = plo[t]; pa[ks][t + 4] = phi[t]; }
    }
    for (int nt = 0; nt < 4; nt++)
      for (int ks = 0; ks < 2; ks++) {
        half8 vbv = *(const half8*)(&Vts[nt * 16 + l15][ks * 32 + quad * 8]);
        Oacc[nt] = __builtin_amdgcn_mfma_f32_16x16x32_f16(pa[ks], vbv, Oacc[nt], 0, 0, 0);
      }
  }

  float osf[4];
  for (int rg = 0; rg < 4; rg++) {
    float s = os[rg];
    for (int m = 1; m < 16; m <<= 1) s += __shfl_xor(s, m, 16);
    osf[rg] = s;
  }

  int b = bh / 12, h = bh - b * 12;
  for (int nt = 0; nt < 4; nt++)
    for (int rg = 0; rg < 4; rg++) {
      int s = i0 + wave * 16 + quad * 4 + rg;
      int d = nt * 16 + l15;
      float v = Oacc[nt][rg] / osf[rg];
      attn[((size_t)(b * 2048 + s)) * 768 + h * 64 + d] = (f16)v;
    }
}

// ---------------------------------------------------------------------------
__global__ __launch_bounds__(256) void k_gemm_out(
    const f16* __restrict__ A, const f16* __restrict__ Bt,
    const float* __restrict__ bias, float* __restrict__ out) {
  __shared__ f16 As[128][72];
  __shared__ f16 Bs[128][72];
  int tid  = threadIdx.x;
  int wave = tid >> 6, lane = tid & 63;
  int quad = lane >> 4, l15 = lane & 15;
  int wm = wave >> 1, wn = wave & 1;
  int m0 = blockIdx.y * 128;
  int n0 = blockIdx.x * 128;

  float4_t acc[4][4] = {};
  int r  = tid >> 3;
  int c8 = (tid & 7) * 8;

  for (int k0 = 0; k0 < 768; k0 += 64) {
    for (int rr = 0; rr < 128; rr += 32) {
      *(uint4*)(&As[r + rr][c8]) =
          *(const uint4*)(A  + (size_t)(m0 + r + rr) * 768 + k0 + c8);
      *(uint4*)(&Bs[r + rr][c8]) =
          *(const uint4*)(Bt + (size_t)(n0 + r + rr) * 768 + k0 + c8);
    }
    __syncthreads();
    half8 af[4][2], bf[4][2];
    for (int mt = 0; mt < 4; mt++)
      for (int ks = 0; ks < 2; ks++)
        af[mt][ks] = *(const half8*)(&As[wm * 64 + mt * 16 + l15][ks * 32 + quad * 8]);
    for (int nt = 0; nt < 4; nt++)
      for (int ks = 0; ks < 2; ks++)
        bf[nt][ks] = *(const half8*)(&Bs[wn * 64 + nt * 16 + l15][ks * 32 + quad * 8]);
    for (int ks = 0; ks < 2; ks++)
      for (int mt = 0; mt < 4; mt++)
        for (int nt = 0; nt < 4; nt++)
          acc[mt][nt] = __builtin_amdgcn_mfma_f32_16x16x32_f16(af[mt][ks], bf[nt][ks],
                                                               acc[mt][nt], 0, 0, 0);
    __syncthreads();
  }

  for (int mt = 0; mt < 4; mt++)
    for (int nt = 0; nt < 4; nt++)
      for (int rg = 0; rg < 4; rg++) {
        int R = m0 + wm * 64 + mt * 16 + quad * 4 + rg;
        int n = n0 + wn * 64 + nt * 16 + l15;
        out[(size_t)R * 768 + n] = acc[mt][nt][rg] + bias[n];
      }
}

// ---------------------------------------------------------------------------
extern "C" void kernel_launch(void* const* d_in, const int* in_sizes, int n_in,
                              void* d_out, int out_size, void* d_ws, size_t ws_size,
                              hipStream_t stream) {
  const float* x     = (const float*)d_in[0];
  const float* Wqkv  = (const float*)d_in[1];
  const float* bqkv  = (const float*)d_in[2];
  const float* Wout  = (const float*)d_in[3];
  const float* bout  = (const float*)d_in[4];
  float* out = (float*)d_out;

  char* ws = (char*)d_ws;
  size_t off = 0;
  f16* xh     = (f16*)(ws + off);
  off += (size_t)M1_ * HID_ * 2;
  f16* wqkvt  = (f16*)(ws + off); off += (size_t)N1_ * HID_ * 2;
  f16* woutt  = (f16*)(ws + off); off += (size_t)HID_ * HID_ * 2;
  f16* Qh     = (f16*)(ws + off); off += (size_t)BH_ * S_ * D_ * 2;
  f16* Kh     = (f16*)(ws + off); off += (size_t)BH_ * S_ * D_ * 2;
  f16* Vt     = (f16*)(ws + off); off += (size_t)BH_ * S_ * D_ * 2;
  float* qq   = (float*)(ws + off); off += (size_t)BH_ * S_ * 4;
  float* kk   = (float*)(ws + off); off += (size_t)BH_ * S_ * 4;
  float* lognc= (float*)(ws + off); off += (size_t)BH_ * S_ * 4;
  f16* attn   = xh;  // xh dead after k_gemm_qkv

  k_convert_x<<<dim3(M1_ * HID_ / 4 / 256), dim3(256), 0, stream>>>(x, xh);
  k_transpose_w<<<dim3(9, 768), dim3(256), 0, stream>>>(Wqkv, wqkvt, N1_, HID_);
  k_transpose_w<<<dim3(3, 768), dim3(256), 0, stream>>>(Wout, woutt, HID_, HID_);

  k_gemm_qkv<<<dim3(N1_ / 128, M1_ / 128), dim3(256), 0, stream>>>(
      xh, wqkvt, bqkv, Qh, Kh, Vt);

  k_norms<<<dim3(BH_ * S_ / 256), dim3(256), 0, stream>>>(Qh, Kh, qq, kk);

  k_colsum<<<dim3(S_ / 64, BH_), dim3(256), 0, stream>>>(Qh, Kh, qq, kk, lognc);

  k_flash<<<dim3(S_ / 64, BH_), dim3(256), 0, stream>>>(
      Qh, Kh, Vt, qq, kk, lognc, attn);

  k_gemm_out<<<dim3(HID_ / 128, M1_ / 128), dim3(256), 0, stream>>>(
      attn, woutt, bout, out);
}

// Round 7
// 484.861 us; speedup vs baseline: 1.2864x; 1.2659x over previous
//
#include <hip/hip_runtime.h>
#include <cstdint>
#include <cstddef>

// Problem constants
#define B_   4
#define S_   2048
#define HID_ 768
#define H_   12
#define D_   64
#define BH_  (B_*H_)        // 48
#define M1_  (B_*S_)        // 8192
#define N1_  (3*HID_)       // 2304
#define PWR  65.5f          // D + alpha

typedef _Float16 f16;
using half4    = __attribute__((ext_vector_type(4))) _Float16;
using half8    = __attribute__((ext_vector_type(8))) _Float16;
using float4_t = __attribute__((ext_vector_type(4))) float;

__device__ __forceinline__ float fexp2(float x) { return __builtin_amdgcn_exp2f(x); }
__device__ __forceinline__ float flog2(float x) { return __builtin_amdgcn_logf(x); }
// raw v_sqrt_f32 (~1 ulp) — avoids the IEEE-correct fixup sequence sqrtf emits
__device__ __forceinline__ float fsqrt(float x) { return __builtin_amdgcn_sqrtf(x); }

// ---------------------------------------------------------------------------
__global__ __launch_bounds__(256) void k_convert_x(const float* __restrict__ x,
                                                   f16* __restrict__ xh) {
  int i = blockIdx.x * 256 + threadIdx.x;
  const float4* xv = (const float4*)x;
  float4 v = xv[i];
  f16 tmp[4] = {(f16)v.x, (f16)v.y, (f16)v.z, (f16)v.w};
  *(uint2*)(xh + 4 * (size_t)i) = *(uint2*)tmp;
}

__global__ __launch_bounds__(256) void k_transpose_w(const float* __restrict__ w,
                                                     f16* __restrict__ wt,
                                                     int N, int K) {
  int n = blockIdx.x * 256 + threadIdx.x;
  int k = blockIdx.y;
  if (n < N) wt[(size_t)n * K + k] = (f16)w[(size_t)k * N + n];
}

// ---------------------------------------------------------------------------
__global__ __launch_bounds__(256) void k_gemm_qkv(
    const f16* __restrict__ A, const f16* __restrict__ Bt,
    const float* __restrict__ bias,
    f16* __restrict__ Qh, f16* __restrict__ Kh, f16* __restrict__ Vt) {
  __shared__ f16 As[128][72];
  __shared__ f16 Bs[128][72];
  int tid  = threadIdx.x;
  int wave = tid >> 6, lane = tid & 63;
  int quad = lane >> 4, l15 = lane & 15;
  int wm = wave >> 1, wn = wave & 1;
  int m0 = blockIdx.y * 128;
  int n0 = blockIdx.x * 128;

  float4_t acc[4][4] = {};
  int r  = tid >> 3;
  int c8 = (tid & 7) * 8;

  for (int k0 = 0; k0 < 768; k0 += 64) {
    for (int rr = 0; rr < 128; rr += 32) {
      *(uint4*)(&As[r + rr][c8]) =
          *(const uint4*)(A  + (size_t)(m0 + r + rr) * 768 + k0 + c8);
      *(uint4*)(&Bs[r + rr][c8]) =
          *(const uint4*)(Bt + (size_t)(n0 + r + rr) * 768 + k0 + c8);
    }
    __syncthreads();
    half8 af[4][2], bf[4][2];
    for (int mt = 0; mt < 4; mt++)
      for (int ks = 0; ks < 2; ks++)
        af[mt][ks] = *(const half8*)(&As[wm * 64 + mt * 16 + l15][ks * 32 + quad * 8]);
    for (int nt = 0; nt < 4; nt++)
      for (int ks = 0; ks < 2; ks++)
        bf[nt][ks] = *(const half8*)(&Bs[wn * 64 + nt * 16 + l15][ks * 32 + quad * 8]);
    for (int ks = 0; ks < 2; ks++)
      for (int mt = 0; mt < 4; mt++)
        for (int nt = 0; nt < 4; nt++)
          acc[mt][nt] = __builtin_amdgcn_mfma_f32_16x16x32_f16(af[mt][ks], bf[nt][ks],
                                                               acc[mt][nt], 0, 0, 0);
    __syncthreads();
  }

  for (int mt = 0; mt < 4; mt++)
    for (int nt = 0; nt < 4; nt++)
      for (int rg = 0; rg < 4; rg++) {
        int R = m0 + wm * 64 + mt * 16 + quad * 4 + rg;
        int n = n0 + wn * 64 + nt * 16 + l15;
        float v = acc[mt][nt][rg] + bias[n];
        int b = R >> 11, s = R & 2047;
        int which = n / 768;
        int rem = n - which * 768;
        int h = rem >> 6, d = rem & 63;
        int bh = b * 12 + h;
        f16 hv = (f16)v;
        if (which == 0)      Qh[((size_t)bh * 2048 + s) * 64 + d] = hv;
        else if (which == 1) Kh[((size_t)bh * 2048 + s) * 64 + d] = hv;
        else                 Vt[((size_t)bh * 64 + d) * 2048 + s] = hv;
      }
}

// ---------------------------------------------------------------------------
__global__ __launch_bounds__(256) void k_norms(const f16* __restrict__ Qh,
                                               const f16* __restrict__ Kh,
                                               float* __restrict__ qq,
                                               float* __restrict__ kk) {
  int i = blockIdx.x * 256 + threadIdx.x;
  if (i >= BH_ * S_) return;
  const f16* p = Qh + (size_t)i * 64;
  float s1 = 0.f, s2 = 0.f;
  for (int d = 0; d < 64; d += 8) {
    half8 v = *(const half8*)(p + d);
    for (int j = 0; j < 8; j++) { float t = (float)v[j]; s1 += t * t; }
  }
  p = Kh + (size_t)i * 64;
  for (int d = 0; d < 64; d += 8) {
    half8 v = *(const half8*)(p + d);
    for (int j = 0; j < 8; j++) { float t = (float)v[j]; s2 += t * t; }
  }
  qq[i] = s1;
  kk[i] = s2;
}

// ---------------------------------------------------------------------------
// Pass 1: column logsumexp of c_ij over i. Online max tracked as running
// min-d2 per column (c monotone in d2): common path has NO cross-lane ops.
// __launch_bounds__(256,4): LDS caps occupancy at 4 waves/SIMD anyway; give
// the allocator the full 128-VGPR budget so acc/d2v arrays don't spill.
__global__ __launch_bounds__(256, 4) void k_colsum(
    const f16* __restrict__ Qh, const f16* __restrict__ Kh,
    const float* __restrict__ qq, const float* __restrict__ kk,
    float* __restrict__ lognc) {
  int bh = blockIdx.y;
  int j0 = blockIdx.x * 64;
  __shared__ f16 Kt[64][72];
  __shared__ f16 Qt[64][72];
  __shared__ float kks[64];
  __shared__ float qqs[64];
  int tid = threadIdx.x;
  int wave = tid >> 6, lane = tid & 63, quad = lane >> 4, l15 = lane & 15;
  int r = tid >> 3, c8 = (tid & 7) * 8;
  const f16* Kb = Kh + (size_t)bh * 2048 * 64;
  const f16* Qb = Qh + (size_t)bh * 2048 * 64;

  for (int rr = 0; rr < 64; rr += 32)
    *(uint4*)(&Kt[r + rr][c8]) = *(const uint4*)(Kb + (size_t)(j0 + r + rr) * 64 + c8);
  if (tid < 64) kks[tid] = kk[bh * 2048 + j0 + tid];
  __syncthreads();

  half8 af[2];
  for (int ks = 0; ks < 2; ks++)
    af[ks] = *(const half8*)(&Kt[wave * 16 + l15][ks * 32 + quad * 8]);
  float kkv[4];
  for (int t = 0; t < 4; t++) kkv[t] = kks[wave * 16 + quad * 4 + t];

  float rm[4], rmind2[4], rs[4];
  for (int t = 0; t < 4; t++) { rm[t] = -1e30f; rmind2[t] = 1e30f; rs[t] = 0.f; }

  for (int it = 0; it < 32; it++) {
    __syncthreads();
    int i0 = it * 64;
    for (int rr = 0; rr < 64; rr += 32)
      *(uint4*)(&Qt[r + rr][c8]) = *(const uint4*)(Qb + (size_t)(i0 + r + rr) * 64 + c8);
    if (tid < 64) qqs[tid] = qq[bh * 2048 + i0 + tid];
    __syncthreads();

    float4_t acc[4] = {};
    for (int nt = 0; nt < 4; nt++)
      for (int ks = 0; ks < 2; ks++) {
        half8 bfv = *(const half8*)(&Qt[nt * 16 + l15][ks * 32 + quad * 8]);
        acc[nt] = __builtin_amdgcn_mfma_f32_16x16x32_f16(af[ks], bfv, acc[nt], 0, 0, 0);
      }

    float d2v[4][4];
    float lmn[4] = {1e30f, 1e30f, 1e30f, 1e30f};
    for (int nt = 0; nt < 4; nt++) {
      float qn = qqs[nt * 16 + l15];
      for (int rg = 0; rg < 4; rg++) {
        float d2 = fmaxf(fmaf(-2.f, acc[nt][rg], kkv[rg] + qn), 0.f);
        d2v[nt][rg] = d2;
        lmn[rg] = fminf(lmn[rg], d2);
      }
    }
    bool noimp = (lmn[0] >= rmind2[0]) & (lmn[1] >= rmind2[1]) &
                 (lmn[2] >= rmind2[2]) & (lmn[3] >= rmind2[3]);
    if (!__all(noimp)) {   // rare: some column's max improved
      for (int rg = 0; rg < 4; rg++) {
        float t = lmn[rg];
        for (int m = 1; m < 16; m <<= 1) t = fminf(t, __shfl_xor(t, m, 16));
        t = fminf(t, rmind2[rg]);
        float nm = -PWR * flog2(1.f + fsqrt(t));
        rs[rg] *= fexp2(rm[rg] - nm);
        rm[rg] = nm; rmind2[rg] = t;
      }
    }
    for (int nt = 0; nt < 4; nt++)
      for (int rg = 0; rg < 4; rg++) {
        float g = fsqrt(d2v[nt][rg]);
        rs[rg] += fexp2(fmaf(-PWR, flog2(1.f + g), -rm[rg]));
      }
  }
  for (int rg = 0; rg < 4; rg++) {
    float s = rs[rg];
    for (int m = 1; m < 16; m <<= 1) s += __shfl_xor(s, m, 16);
    if (l15 == 0) {
      int j = j0 + wave * 16 + quad * 4 + rg;
      lognc[bh * 2048 + j] = rm[rg] + flog2(s);
    }
  }
}

// ---------------------------------------------------------------------------
// Pass 2: flash with biased logits m = c - 0.5*lognc_j. Lazy online max.
__global__ __launch_bounds__(256, 4) void k_flash(
    const f16* __restrict__ Qh, const f16* __restrict__ Kh, const f16* __restrict__ Vt,
    const float* __restrict__ qq, const float* __restrict__ kk,
    const float* __restrict__ lognc, f16* __restrict__ attn) {
  int bh = blockIdx.y;
  int i0 = blockIdx.x * 64;
  __shared__ f16 Qt[64][72];
  __shared__ f16 Kt[64][72];
  __shared__ f16 Vts[64][72];           // [d][j]
  __shared__ float qqs[64], kks[64], lns[64];   // lns = -0.5*log2(N_C)
  __shared__ f16 Plds[4][16][68];
  int tid = threadIdx.x;
  int wave = tid >> 6, lane = tid & 63, quad = lane >> 4, l15 = lane & 15;
  int r = tid >> 3, c8 = (tid & 7) * 8;
  const f16* Qb = Qh + (size_t)bh * 2048 * 64;
  const f16* Kb = Kh + (size_t)bh * 2048 * 64;
  const f16* Vb = Vt + (size_t)bh * 64 * 2048;

  for (int rr = 0; rr < 64; rr += 32)
    *(uint4*)(&Qt[r + rr][c8]) = *(const uint4*)(Qb + (size_t)(i0 + r + rr) * 64 + c8);
  if (tid < 64) qqs[tid] = qq[bh * 2048 + i0 + tid];
  __syncthreads();

  half8 af[2];
  for (int ks = 0; ks < 2; ks++)
    af[ks] = *(const half8*)(&Qt[wave * 16 + l15][ks * 32 + quad * 8]);
  float qv[4];
  for (int t = 0; t < 4; t++) qv[t] = qqs[wave * 16 + quad * 4 + t];

  float rm[4], os[4];
  float4_t Oacc[4] = {};
  for (int t = 0; t < 4; t++) { rm[t] = -1e30f; os[t] = 0.f; }

  for (int jt = 0; jt < 32; jt++) {
    __syncthreads();
    int j0 = jt * 64;
    for (int rr = 0; rr < 64; rr += 32) {
      *(uint4*)(&Kt[r + rr][c8]) =
          *(const uint4*)(Kb + (size_t)(j0 + r + rr) * 64 + c8);
      *(uint4*)(&Vts[r + rr][c8]) =
          *(const uint4*)(Vb + (size_t)(r + rr) * 2048 + j0 + c8);
    }
    if (tid < 64) {
      kks[tid] = kk[bh * 2048 + j0 + tid];
      lns[tid] = -0.5f * lognc[bh * 2048 + j0 + tid];
    }
    __syncthreads();

    float4_t acc[4] = {};
    for (int nt = 0; nt < 4; nt++)
      for (int ks = 0; ks < 2; ks++) {
        half8 bfv = *(const half8*)(&Kt[nt * 16 + l15][ks * 32 + quad * 8]);
        acc[nt] = __builtin_amdgcn_mfma_f32_16x16x32_f16(af[ks], bfv, acc[nt], 0, 0, 0);
      }

    // biased logits + per-lane tile max per row
    float mv[4][4];
    float lmx[4] = {-1e30f, -1e30f, -1e30f, -1e30f};
    for (int nt = 0; nt < 4; nt++) {
      float kn = kks[nt * 16 + l15];
      float bias = lns[nt * 16 + l15];
      for (int rg = 0; rg < 4; rg++) {
        float d2 = fmaxf(fmaf(-2.f, acc[nt][rg], qv[rg] + kn), 0.f);
        float g = fsqrt(d2);
        float m = fmaf(-PWR, flog2(1.f + g), bias);
        mv[nt][rg] = m;
        lmx[rg] = fmaxf(lmx[rg], m);
      }
    }
    bool noimp = (lmx[0] <= rm[0]) & (lmx[1] <= rm[1]) &
                 (lmx[2] <= rm[2]) & (lmx[3] <= rm[3]);
    if (!__all(noimp)) {   // rare: some row's max improved -> reduce + rescale
      for (int rg = 0; rg < 4; rg++) {
        float t = lmx[rg];
        for (int m = 1; m < 16; m <<= 1) t = fmaxf(t, __shfl_xor(t, m, 16));
        t = fmaxf(t, rm[rg]);
        float a = fexp2(rm[rg] - t);
        os[rg] *= a;
        Oacc[0][rg] *= a; Oacc[1][rg] *= a; Oacc[2][rg] *= a; Oacc[3][rg] *= a;
        rm[rg] = t;
      }
    }

    for (int nt = 0; nt < 4; nt++)
      for (int rg = 0; rg < 4; rg++) {
        float p = fexp2(mv[nt][rg] - rm[rg]);   // <= 1 guaranteed
        os[rg] += p;
        Plds[wave][quad * 4 + rg][nt * 16 + l15] = (f16)p;
      }
    __syncthreads();   // order P writes before A-frag reads

    half8 pa[2];
    for (int ks = 0; ks < 2; ks++) {
      half4 plo = *(const half4*)(&Plds[wave][l15][ks * 32 + quad * 8]);
      half4 phi = *(const half4*)(&Plds[wave][l15][ks * 32 + quad * 8 + 4]);
      for (int t = 0; t < 4; t++) { pa[ks][t] = plo[t]; pa[ks][t + 4] = phi[t]; }
    }
    for (int nt = 0; nt < 4; nt++)
      for (int ks = 0; ks < 2; ks++) {
        half8 vbv = *(const half8*)(&Vts[nt * 16 + l15][ks * 32 + quad * 8]);
        Oacc[nt] = __builtin_amdgcn_mfma_f32_16x16x32_f16(pa[ks], vbv, Oacc[nt], 0, 0, 0);
      }
  }

  float osf[4];
  for (int rg = 0; rg < 4; rg++) {
    float s = os[rg];
    for (int m = 1; m < 16; m <<= 1) s += __shfl_xor(s, m, 16);
    osf[rg] = s;
  }

  int b = bh / 12, h = bh - b * 12;
  for (int nt = 0; nt < 4; nt++)
    for (int rg = 0; rg < 4; rg++) {
      int s = i0 + wave * 16 + quad * 4 + rg;
      int d = nt * 16 + l15;
      float v = Oacc[nt][rg] / osf[rg];
      attn[((size_t)(b * 2048 + s)) * 768 + h * 64 + d] = (f16)v;
    }
}

// ---------------------------------------------------------------------------
__global__ __launch_bounds__(256) void k_gemm_out(
    const f16* __restrict__ A, const f16* __restrict__ Bt,
    const float* __restrict__ bias, float* __restrict__ out) {
  __shared__ f16 As[128][72];
  __shared__ f16 Bs[128][72];
  int tid  = threadIdx.x;
  int wave = tid >> 6, lane = tid & 63;
  int quad = lane >> 4, l15 = lane & 15;
  int wm = wave >> 1, wn = wave & 1;
  int m0 = blockIdx.y * 128;
  int n0 = blockIdx.x * 128;

  float4_t acc[4][4] = {};
  int r  = tid >> 3;
  int c8 = (tid & 7) * 8;

  for (int k0 = 0; k0 < 768; k0 += 64) {
    for (int rr = 0; rr < 128; rr += 32) {
      *(uint4*)(&As[r + rr][c8]) =
          *(const uint4*)(A  + (size_t)(m0 + r + rr) * 768 + k0 + c8);
      *(uint4*)(&Bs[r + rr][c8]) =
          *(const uint4*)(Bt + (size_t)(n0 + r + rr) * 768 + k0 + c8);
    }
    __syncthreads();
    half8 af[4][2], bf[4][2];
    for (int mt = 0; mt < 4; mt++)
      for (int ks = 0; ks < 2; ks++)
        af[mt][ks] = *(const half8*)(&As[wm * 64 + mt * 16 + l15][ks * 32 + quad * 8]);
    for (int nt = 0; nt < 4; nt++)
      for (int ks = 0; ks < 2; ks++)
        bf[nt][ks] = *(const half8*)(&Bs[wn * 64 + nt * 16 + l15][ks * 32 + quad * 8]);
    for (int ks = 0; ks < 2; ks++)
      for (int mt = 0; mt < 4; mt++)
        for (int nt = 0; nt < 4; nt++)
          acc[mt][nt] = __builtin_amdgcn_mfma_f32_16x16x32_f16(af[mt][ks], bf[nt][ks],
                                                               acc[mt][nt], 0, 0, 0);
    __syncthreads();
  }

  for (int mt = 0; mt < 4; mt++)
    for (int nt = 0; nt < 4; nt++)
      for (int rg = 0; rg < 4; rg++) {
        int R = m0 + wm * 64 + mt * 16 + quad * 4 + rg;
        int n = n0 + wn * 64 + nt * 16 + l15;
        out[(size_t)R * 768 + n] = acc[mt][nt][rg] + bias[n];
      }
}

// ---------------------------------------------------------------------------
extern "C" void kernel_launch(void* const* d_in, const int* in_sizes, int n_in,
                              void* d_out, int out_size, void* d_ws, size_t ws_size,
                              hipStream_t stream) {
  const float* x     = (const float*)d_in[0];
  const float* Wqkv  = (const float*)d_in[1];
  const float* bqkv  = (const float*)d_in[2];
  const float* Wout  = (const float*)d_in[3];
  const float* bout  = (const float*)d_in[4];
  float* out = (float*)d_out;

  char* ws = (char*)d_ws;
  size_t off = 0;
  f16* xh     = (f16*)(ws + off);
  off += (size_t)M1_ * HID_ * 2;
  f16* wqkvt  = (f16*)(ws + off); off += (size_t)N1_ * HID_ * 2;
  f16* woutt  = (f16*)(ws + off); off += (size_t)HID_ * HID_ * 2;
  f16* Qh     = (f16*)(ws + off); off += (size_t)BH_ * S_ * D_ * 2;
  f16* Kh     = (f16*)(ws + off); off += (size_t)BH_ * S_ * D_ * 2;
  f16* Vt     = (f16*)(ws + off); off += (size_t)BH_ * S_ * D_ * 2;
  float* qq   = (float*)(ws + off); off += (size_t)BH_ * S_ * 4;
  float* kk   = (float*)(ws + off); off += (size_t)BH_ * S_ * 4;
  float* lognc= (float*)(ws + off); off += (size_t)BH_ * S_ * 4;
  f16* attn   = xh;  // xh dead after k_gemm_qkv

  k_convert_x<<<dim3(M1_ * HID_ / 4 / 256), dim3(256), 0, stream>>>(x, xh);
  k_transpose_w<<<dim3(9, 768), dim3(256), 0, stream>>>(Wqkv, wqkvt, N1_, HID_);
  k_transpose_w<<<dim3(3, 768), dim3(256), 0, stream>>>(Wout, woutt, HID_, HID_);

  k_gemm_qkv<<<dim3(N1_ / 128, M1_ / 128), dim3(256), 0, stream>>>(
      xh, wqkvt, bqkv, Qh, Kh, Vt);

  k_norms<<<dim3(BH_ * S_ / 256), dim3(256), 0, stream>>>(Qh, Kh, qq, kk);

  k_colsum<<<dim3(S_ / 64, BH_), dim3(256), 0, stream>>>(Qh, Kh, qq, kk, lognc);

  k_flash<<<dim3(S_ / 64, BH_), dim3(256), 0, stream>>>(
      Qh, Kh, Vt, qq, kk, lognc, attn);

  k_gemm_out<<<dim3(HID_ / 128, M1_ / 128), dim3(256), 0, stream>>>(
      attn, woutt, bout, out);
}